// Round 3
// baseline (424.030 us; speedup 1.0000x reference)
//
#include <hip/hip_runtime.h>

// DenseGINConv fused: out = mask * ( relu( ((1+eps)*x + adj@x) @ W1 + b1 ) @ W2 + b2 )
// B=64, N=1024, F_IN=64, F_HID=128, F_OUT=64, fp32 in/out.
//
// Round 8: eliminate workspace use (the harness re-poisons a 1-GiB d_ws with a
// 160 us fillBuffer each iteration -- the top-5 dispatches are ALL these fills).
//  - xt_pack pre-kernel + d_ws dropped. B-fragments are now built in-kernel:
//    per chunk, the 64x64 x-slab is staged to LDS in B-frag-unit layout.
//    Unit (g,f) = 8 bf16 x[c*64+g*8+k][f] at slot g*64 + (f>>1) + ((f&1)<<5).
//    The f-bit interleave makes BOTH ds_write_b128 (lanes sweep contiguous
//    slots) and the B-frag ds_read_b128 (4 dwords/bank = structural min)
//    conflict-free and 16-B aligned. Register content identical to xt path.
//  - Depth-2 pipeline + raw s_barrier + counted vmcnt (round-7 structure) kept.
//  - Phases B/C + epilogue + m74/m101-verified MFMA layouts unchanged.
//
// LDS: adj bf16 dbuf 18432 B + xs dbuf 16384 B = 34816 B (h1s 33792 aliases)
//      + hs 17408 B = 52224 B -> 3 blocks/CU. __launch_bounds__(256,3).

#define N_     1024
#define FIN    64
#define FHID   128
#define FOUT   64
#define HS_LD  68
#define H1_LD  132
#define CH     64      // j-chunk size
#define NCHUNK 16      // 1024 / 64
#define KSPC   4       // k-steps (of 16) per chunk
#define FROW   9       // s16x8 per adj row: 8 used + 1 pad -> 144 B stride
#define AUNITS 18      // s16x4 (8 B) units per adj row
#define ABUFU  1152    // s16x4 units per adj buffer (64 * 18) = 9216 B
#define ADJ_BYTES 18432
#define XSU    512     // s16x8 units per xs buffer (8 KB)

typedef __attribute__((ext_vector_type(16))) float f32x16;
typedef __attribute__((ext_vector_type(8)))  short s16x8;
typedef __attribute__((ext_vector_type(4)))  short s16x4;

__device__ inline short f2bf(float f) {
    union { float f; unsigned int u; } v; v.f = f;
    unsigned int r = v.u + 0x7fffu + ((v.u >> 16) & 1u);   // RNE
    return (short)(r >> 16);
}

__global__ __launch_bounds__(256, 3) void gin_main(
    const float* __restrict__ x, const float* __restrict__ adj,
    const int* __restrict__ mask, const float* __restrict__ W1,
    const float* __restrict__ b1, const float* __restrict__ W2,
    const float* __restrict__ b2, const float* __restrict__ epsp,
    float* __restrict__ out)
{
    __shared__ __align__(16) char region_raw[34816];   // adj dbuf + xs dbuf / h1s
    __shared__ float hs[64 * HS_LD];

    auto   asf  = reinterpret_cast<s16x8 (*)[64][FROW]>(region_raw);
    s16x4* asf4 = reinterpret_cast<s16x4*>(region_raw);
    s16x8* xsb  = reinterpret_cast<s16x8*>(region_raw + ADJ_BYTES);
    float* h1s  = reinterpret_cast<float*>(region_raw);

    const int t    = threadIdx.x;
    const int lane = t & 63;
    const int w    = t >> 6;
    const int b    = blockIdx.x >> 4;
    const int i0   = (blockIdx.x & 15) * 64;

    const float* xb   = x   + (size_t)b * N_ * FIN;
    const float* adjb = adj + (size_t)b * N_ * N_ + (size_t)i0 * N_;

    // 32x32x16 MFMA addressing (m74/m101-verified)
    const int l31  = lane & 31;
    const int half = lane >> 5;
    const int mrow = (w & 1) * 32;
    const int ncol = (w >> 1) * 32;
    const int ngq  = (w >> 1);

    // adj staging (coalesced): pass q covers row q*16 + (t>>4), cols (t&15)*4 .. +3
    const int rq16 = t >> 4;        // 0..15
    const int cl16 = t & 15;        // 0..15
    const float* adjA = adjb + (size_t)rq16 * N_ + cl16 * 4;

    // x staging: thread owns units (gx, 2*mx) and (gx, 2*mx+1)
    const int gx = t >> 5;          // 0..7
    const int mx = t & 31;          // 0..31
    const float* xrow0 = xb + (size_t)(gx * 8) * FIN + 2 * mx;
    const int slotA = gx * 64 + mx;           // unit slot for f = 2*mx

    // B-frag read slot base: f = ngq*32 + l31 -> (f>>1) + ((f&1)<<5)
    const int sbase = ngq * 16 + (l31 >> 1) + ((l31 & 1) << 5);

    f32x16 acc;
    #pragma unroll
    for (int r = 0; r < 16; ++r) acc[r] = 0.f;

    float4 areg[2][4];   // adj prefetch, 2 chunks in flight
    float2 xregf[2][8];  // x prefetch, 2 chunks in flight

    #define ISSUE_A(p, c_) { _Pragma("unroll") for (int q = 0; q < 4; ++q) \
        areg[p][q] = *reinterpret_cast<const float4*>(adjA + (size_t)q * 16 * N_ + (size_t)(c_) * CH); }
    #define ISSUE_X(p, c_) { _Pragma("unroll") for (int k = 0; k < 8; ++k) \
        xregf[p][k] = *reinterpret_cast<const float2*>(xrow0 + (size_t)((c_) * CH + k) * FIN); }
    #define STAGE_A(o, p) { _Pragma("unroll") for (int q = 0; q < 4; ++q) { \
        const float4 u = areg[p][q]; s16x4 fr; \
        fr[0] = f2bf(u.x); fr[1] = f2bf(u.y); fr[2] = f2bf(u.z); fr[3] = f2bf(u.w); \
        asf4[(o) * ABUFU + (q * 16 + rq16) * AUNITS + cl16] = fr; } }
    #define STAGE_X(o, p) { s16x8 frA, frB; \
        _Pragma("unroll") for (int k = 0; k < 8; ++k) { \
            frA[k] = f2bf(xregf[p][k].x); frB[k] = f2bf(xregf[p][k].y); } \
        xsb[(o) * XSU + slotA] = frA; xsb[(o) * XSU + slotA + 32] = frB; }

    // ---- prologue: issue chunks 0,1; stage chunk 0 ----
    ISSUE_A(0, 0); ISSUE_A(1, 1);
    ISSUE_X(0, 0); ISSUE_X(1, 1);
    STAGE_A(0, 0);
    STAGE_X(0, 0);
    asm volatile("s_waitcnt lgkmcnt(0)" ::: "memory");
    __builtin_amdgcn_s_barrier();

    // ---- depth-2 pipelined chunk loop (raw barriers: no vmcnt(0) drain) ----
    #pragma unroll
    for (int c = 0; c < NCHUNK; ++c) {
        if (c + 2 < NCHUNK) {
            ISSUE_A(c & 1, c + 2);
            ISSUE_X(c & 1, c + 2);
        }
        // compute chunk c from buffer c&1
        #pragma unroll
        for (int s = 0; s < KSPC; ++s) {
            const s16x8 a  = asf[c & 1][mrow + l31][2 * s + half];
            const s16x8 bb = xsb[(c & 1) * XSU + (s * 2 + half) * 64 + sbase];
            acc = __builtin_amdgcn_mfma_f32_32x32x16_bf16(a, bb, acc, 0, 0, 0);
        }
        if (c + 1 < NCHUNK) {
            STAGE_A((c + 1) & 1, (c + 1) & 1);
            STAGE_X((c + 1) & 1, (c + 1) & 1);
            asm volatile("s_waitcnt lgkmcnt(0)" ::: "memory");
            __builtin_amdgcn_s_barrier();
        }
    }

    // h = (1+eps)*x + agg -> hs  (C/D: col=lane&31, row=(reg&3)+8*(reg>>2)+4*half)
    {
        const float se = 1.0f + epsp[0];
        const int col = ncol + l31;
        #pragma unroll
        for (int reg = 0; reg < 16; ++reg) {
            const int row = mrow + (reg & 3) + 8 * (reg >> 2) + 4 * half;
            const float xv = xb[(size_t)(i0 + row) * FIN + col];
            hs[row * HS_LD + col] = acc[reg] + se * xv;
        }
    }
    __syncthreads();

    // ---------------- Phase B: h1 = relu(h @ W1 + b1) ----------------
    {
        const int k4 = (t & 31) * 4;
        const int rb = (t >> 5) * 8;
        float4 hacc[8];
        const float4 b1v = *reinterpret_cast<const float4*>(b1 + k4);
        #pragma unroll
        for (int r = 0; r < 8; ++r) hacc[r] = b1v;

        #pragma unroll 4
        for (int j = 0; j < FIN; ++j) {
            const float4 w1v = *reinterpret_cast<const float4*>(W1 + j * FHID + k4);
            #pragma unroll
            for (int r = 0; r < 8; ++r) {
                const float hv = hs[(rb + r) * HS_LD + j];
                hacc[r].x += hv * w1v.x; hacc[r].y += hv * w1v.y;
                hacc[r].z += hv * w1v.z; hacc[r].w += hv * w1v.w;
            }
        }
        #pragma unroll
        for (int r = 0; r < 8; ++r) {
            float4 v;
            v.x = fmaxf(hacc[r].x, 0.f); v.y = fmaxf(hacc[r].y, 0.f);
            v.z = fmaxf(hacc[r].z, 0.f); v.w = fmaxf(hacc[r].w, 0.f);
            *reinterpret_cast<float4*>(&h1s[(rb + r) * H1_LD + k4]) = v;
        }
    }
    __syncthreads();

    // ---------------- Phase C: out = mask * (h1 @ W2 + b2) ----------------
    {
        const int fi = (t & 15) * 4;
        const int ri = (t >> 4) * 4;
        float4 oacc[4];
        const float4 b2v = *reinterpret_cast<const float4*>(b2 + fi);
        #pragma unroll
        for (int ii = 0; ii < 4; ++ii) oacc[ii] = b2v;

        #pragma unroll 4
        for (int j = 0; j < FHID; ++j) {
            const float4 w2v = *reinterpret_cast<const float4*>(W2 + j * FOUT + fi);
            #pragma unroll
            for (int ii = 0; ii < 4; ++ii) {
                const float hv = h1s[(ri + ii) * H1_LD + j];
                oacc[ii].x += hv * w2v.x; oacc[ii].y += hv * w2v.y;
                oacc[ii].z += hv * w2v.z; oacc[ii].w += hv * w2v.w;
            }
        }
        #pragma unroll
        for (int ii = 0; ii < 4; ++ii) {
            const int gi = i0 + ri + ii;
            const int m  = mask[b * N_ + gi];
            float4 o = oacc[ii];
            if (!m) o = make_float4(0.f, 0.f, 0.f, 0.f);
            *reinterpret_cast<float4*>(out + ((size_t)b * N_ + gi) * FOUT + fi) = o;
        }
    }
}

extern "C" void kernel_launch(void* const* d_in, const int* in_sizes, int n_in,
                              void* d_out, int out_size, void* d_ws, size_t ws_size,
                              hipStream_t stream) {
    const float* x    = (const float*)d_in[0];
    const float* adj  = (const float*)d_in[1];
    const int*   mask = (const int*)  d_in[2];
    const float* W1   = (const float*)d_in[3];
    const float* b1   = (const float*)d_in[4];
    const float* W2   = (const float*)d_in[5];
    const float* b2   = (const float*)d_in[6];
    const float* eps  = (const float*)d_in[7];
    float* out = (float*)d_out;
    (void)d_ws; (void)ws_size;   // workspace intentionally unused

    gin_main<<<dim3(64 * 16), dim3(256), 0, stream>>>(x, adj, mask, W1, b1, W2, b2, eps, out);
}

// Round 5
// 398.538 us; speedup vs baseline: 1.0640x; 1.0640x over previous
//
#include <hip/hip_runtime.h>

// DenseGINConv fused: out = mask * ( relu( ((1+eps)*x + adj@x) @ W1 + b1 ) @ W2 + b2 )
// B=64, N=1024, F_IN=64, F_HID=128, F_OUT=64, fp32 in/out.
//
// Round 10 = Round 9 resubmitted verbatim (R9 bench died to infra:
// "MI355X container failed twice"; kernel re-audited, no defect found).
//  (a) LDS 52224 -> 34816 B => 4 blocks/CU, all 1024 blocks co-resident
//      (kills the 256-block tail round at 1/3 parallelism);
//  (b) phases B/C moved from fp32 VALU (~13.6 us GPU-wide) to MFMA (~1 us)
//      using the same m74/m101-verified fragment layouts as phase A;
//  (c) h and h1 stored bf16 with the G4 XOR swizzle (byte ^= (row&7)<<4)
//      -- conflict-free ds_read_b128 A-frags.
//  W1/W2 pre-packed to bf16 B-frag units in d_ws by a tiny wpack kernel
//  (R8 proved the 1-GiB d_ws poison fill is unconditional, so ws use is free).
//  Phase A = R8 structure (depth-2 adj pipeline, raw s_barrier, counted vmcnt),
//  x-prefetch depth-1 to fit 128 VGPR at __launch_bounds__(256,4).
//
// LDS: single 34816 B region. Phase A: adj dbuf [0,18432) + xs dbuf [18432,34816).
// After barrier: h bf16 [0,8192) (row*128+col*2 ^ XOR), h1 bf16 [8192,24576)
// (row*256+col*2 ^ XOR). 34816*4 = 139264 <= 163840 -> 4 blocks/CU.

#define N_     1024
#define FIN    64
#define FHID   128
#define FOUT   64
#define CH     64      // j-chunk size
#define NCHUNK 16      // 1024 / 64
#define KSPC   4       // k-steps (of 16) per chunk
#define AUNITS 18      // s16x4 (8 B) units per adj row (16 used + 2 pad)
#define ABUFU  1152    // s16x4 units per adj buffer (9216 B)
#define ADJ_BYTES 18432
#define XSU    512     // s16x8 units per xs buffer (8 KB)
#define H1OFF  8192    // h1 bf16 base byte in region
#define REGION 34816

typedef __attribute__((ext_vector_type(16))) float f32x16;
typedef __attribute__((ext_vector_type(8)))  short s16x8;
typedef __attribute__((ext_vector_type(4)))  short s16x4;

__device__ inline short f2bf(float f) {
    union { float f; unsigned int u; } v; v.f = f;
    unsigned int r = v.u + 0x7fffu + ((v.u >> 16) & 1u);   // RNE
    return (short)(r >> 16);
}

// ---- wpack: W1 (64x128) and W2 (128x64) -> bf16 B-frag units in d_ws ----
// W1 unit u = ks2*128 + col (ks2=0..7): 8 bf16 W1[ks2*8+k][col], k=0..7.
// W2 unit 1024 + ks2*64 + col (ks2=0..15): W2[ks2*8+k][col].
__global__ __launch_bounds__(256) void wpack(const float* __restrict__ W1,
                                             const float* __restrict__ W2,
                                             s16x8* __restrict__ wf)
{
    const int u = blockIdx.x * 256 + threadIdx.x;   // 0..2047
    s16x8 fr;
    if (u < 1024) {
        const int ks2 = u >> 7, col = u & 127;
        #pragma unroll
        for (int k = 0; k < 8; ++k) fr[k] = f2bf(W1[(ks2 * 8 + k) * FHID + col]);
    } else {
        const int v = u - 1024;
        const int ks2 = v >> 6, col = v & 63;
        #pragma unroll
        for (int k = 0; k < 8; ++k) fr[k] = f2bf(W2[(ks2 * 8 + k) * FOUT + col]);
    }
    wf[u] = fr;
}

// ---------------- main kernel ----------------
__global__ __launch_bounds__(256, 4) void gin_main(
    const float* __restrict__ x, const float* __restrict__ adj,
    const int* __restrict__ mask, const float* __restrict__ b1,
    const float* __restrict__ b2, const float* __restrict__ epsp,
    const s16x8* __restrict__ wf, float* __restrict__ out)
{
    __shared__ __align__(16) char region_raw[REGION];

    auto   asf  = reinterpret_cast<s16x8 (*)[64][AUNITS / 2]>(region_raw);
    s16x4* asf4 = reinterpret_cast<s16x4*>(region_raw);
    s16x8* xsb  = reinterpret_cast<s16x8*>(region_raw + ADJ_BYTES);

    const int t    = threadIdx.x;
    const int lane = t & 63;
    const int w    = t >> 6;
    const int b    = blockIdx.x >> 4;
    const int i0   = (blockIdx.x & 15) * 64;

    const float* xb   = x   + (size_t)b * N_ * FIN;
    const float* adjb = adj + (size_t)b * N_ * N_ + (size_t)i0 * N_;

    // 32x32x16 MFMA addressing (m74/m101-verified)
    const int l31  = lane & 31;
    const int half = lane >> 5;
    const int mrow = (w & 1) * 32;        // phase-A tile row
    const int ngq  = (w >> 1);            // phase-A tile col group (0/1)
    const int ncol = ngq * 32;

    // adj staging (coalesced): pass q covers row q*16 + (t>>4), cols (t&15)*4 .. +3
    const int rq16 = t >> 4;
    const int cl16 = t & 15;
    const float* adjA = adjb + (size_t)rq16 * N_ + cl16 * 4;

    // x staging: thread owns units (gx, 2*mx) and (gx, 2*mx+1)
    const int gx = t >> 5;
    const int mx = t & 31;
    const float* xrow0 = xb + (size_t)(gx * 8) * FIN + 2 * mx;
    const int slotA = gx * 64 + mx;

    // B-frag read slot base: f = ngq*32 + l31 -> (f>>1) + ((f&1)<<5)
    const int sbase = ngq * 16 + (l31 >> 1) + ((l31 & 1) << 5);

    f32x16 acc;
    #pragma unroll
    for (int r = 0; r < 16; ++r) acc[r] = 0.f;

    float4 areg[2][4];   // adj prefetch, 2 chunks in flight
    float2 xregf[8];     // x prefetch, depth-1

    #define ISSUE_A(p, c_) { _Pragma("unroll") for (int q = 0; q < 4; ++q) \
        areg[p][q] = *reinterpret_cast<const float4*>(adjA + (size_t)q * 16 * N_ + (size_t)(c_) * CH); }
    #define ISSUE_X(c_) { _Pragma("unroll") for (int k = 0; k < 8; ++k) \
        xregf[k] = *reinterpret_cast<const float2*>(xrow0 + (size_t)((c_) * CH + k) * FIN); }
    #define STAGE_A(o, p) { _Pragma("unroll") for (int q = 0; q < 4; ++q) { \
        const float4 u = areg[p][q]; s16x4 fr; \
        fr[0] = f2bf(u.x); fr[1] = f2bf(u.y); fr[2] = f2bf(u.z); fr[3] = f2bf(u.w); \
        asf4[(o) * ABUFU + (q * 16 + rq16) * AUNITS + cl16] = fr; } }
    #define STAGE_X(o) { s16x8 frA, frB; \
        _Pragma("unroll") for (int k = 0; k < 8; ++k) { \
            frA[k] = f2bf(xregf[k].x); frB[k] = f2bf(xregf[k].y); } \
        xsb[(o) * XSU + slotA] = frA; xsb[(o) * XSU + slotA + 32] = frB; }

    // ---- prologue ----
    ISSUE_A(0, 0); ISSUE_A(1, 1);
    ISSUE_X(0);
    STAGE_A(0, 0);
    STAGE_X(0);
    asm volatile("s_waitcnt lgkmcnt(0)" ::: "memory");
    __builtin_amdgcn_s_barrier();

    // ---- depth-2 pipelined chunk loop (raw barriers: no vmcnt(0) drain) ----
    #pragma unroll
    for (int c = 0; c < NCHUNK; ++c) {
        if (c + 2 < NCHUNK) ISSUE_A(c & 1, c + 2);
        if (c + 1 < NCHUNK) ISSUE_X(c + 1);
        #pragma unroll
        for (int s = 0; s < KSPC; ++s) {
            const s16x8 a  = asf[c & 1][mrow + l31][2 * s + half];
            const s16x8 bb = xsb[(c & 1) * XSU + (s * 2 + half) * 64 + sbase];
            acc = __builtin_amdgcn_mfma_f32_32x32x16_bf16(a, bb, acc, 0, 0, 0);
        }
        if (c + 1 < NCHUNK) {
            STAGE_A((c + 1) & 1, (c + 1) & 1);
            STAGE_X((c + 1) & 1);
            asm volatile("s_waitcnt lgkmcnt(0)" ::: "memory");
            __builtin_amdgcn_s_barrier();
        }
    }
    __syncthreads();   // last chunk's ds_reads retired (MFMA dep) in all waves

    // ---- epilogue A: h = (1+eps)*x + agg -> bf16 LDS [0,8192), XOR-swizzled ----
    // C/D: col=lane&31, row=(reg&3)+8*(reg>>2)+4*half.
    {
        const float se = 1.0f + epsp[0];
        const int col = ncol + l31;
        #pragma unroll
        for (int r = 0; r < 16; ++r) {
            const int row = mrow + (r & 3) + 8 * (r >> 2) + 4 * half;
            const float xv = xb[(size_t)(i0 + row) * FIN + col];
            const float hv = acc[r] + se * xv;
            const int byte = (row * 128 + col * 2) ^ ((row & 7) << 4);
            *reinterpret_cast<unsigned short*>(region_raw + byte) = (unsigned short)f2bf(hv);
        }
    }
    __syncthreads();

    // ---- Phase B: h1 = relu(h @ W1 + b1), MFMA. 8 tiles, 2 per wave ----
    {
        const int mB  = w & 1;
        const int nB0 = w >> 1;            // tiles nB0 and nB0+2
        f32x16 acc0, acc1;
        const float bv0 = b1[nB0 * 32 + l31];
        const float bv1 = b1[(nB0 + 2) * 32 + l31];
        #pragma unroll
        for (int r = 0; r < 16; ++r) { acc0[r] = bv0; acc1[r] = bv1; }
        const int hrow = mB * 32 + l31;
        #pragma unroll
        for (int ks = 0; ks < 4; ++ks) {
            const int hb = (hrow * 128 + ks * 32 + half * 16) ^ ((hrow & 7) << 4);
            const s16x8 a   = *reinterpret_cast<const s16x8*>(region_raw + hb);
            const s16x8 w1a = wf[(ks * 2 + half) * 128 + nB0 * 32 + l31];
            const s16x8 w1b = wf[(ks * 2 + half) * 128 + (nB0 + 2) * 32 + l31];
            acc0 = __builtin_amdgcn_mfma_f32_32x32x16_bf16(a, w1a, acc0, 0, 0, 0);
            acc1 = __builtin_amdgcn_mfma_f32_32x32x16_bf16(a, w1b, acc1, 0, 0, 0);
        }
        __syncthreads();   // order h-reads before h1 writes (region aliasing hygiene)
        #pragma unroll
        for (int r = 0; r < 16; ++r) {
            const int row = mB * 32 + (r & 3) + 8 * (r >> 2) + 4 * half;
            const int c0 = nB0 * 32 + l31, c1 = (nB0 + 2) * 32 + l31;
            const int y0 = H1OFF + ((row * 256 + c0 * 2) ^ ((row & 7) << 4));
            const int y1 = H1OFF + ((row * 256 + c1 * 2) ^ ((row & 7) << 4));
            *reinterpret_cast<unsigned short*>(region_raw + y0) =
                (unsigned short)f2bf(fmaxf(acc0[r], 0.f));
            *reinterpret_cast<unsigned short*>(region_raw + y1) =
                (unsigned short)f2bf(fmaxf(acc1[r], 0.f));
        }
    }
    __syncthreads();

    // ---- Phase C: out = mask * (h1 @ W2 + b2), MFMA. 4 tiles, 1 per wave ----
    {
        const int mo = w & 1;
        const int no = w >> 1;             // 0 or 1
        f32x16 accC;
        const float bv = b2[no * 32 + l31];
        #pragma unroll
        for (int r = 0; r < 16; ++r) accC[r] = bv;
        const int arow = mo * 32 + l31;
        #pragma unroll
        for (int ks = 0; ks < 8; ++ks) {
            const int hb = H1OFF + ((arow * 256 + ks * 32 + half * 16) ^ ((arow & 7) << 4));
            const s16x8 a  = *reinterpret_cast<const s16x8*>(region_raw + hb);
            const s16x8 wb = wf[1024 + (ks * 2 + half) * 64 + no * 32 + l31];
            accC = __builtin_amdgcn_mfma_f32_32x32x16_bf16(a, wb, accC, 0, 0, 0);
        }
        const int col = no * 32 + l31;
        #pragma unroll
        for (int r = 0; r < 16; ++r) {
            const int row = mo * 32 + (r & 3) + 8 * (r >> 2) + 4 * half;
            const int gi = i0 + row;
            const float v = mask[b * N_ + gi] ? accC[r] : 0.f;
            out[((size_t)b * N_ + gi) * FOUT + col] = v;
        }
    }
}

extern "C" void kernel_launch(void* const* d_in, const int* in_sizes, int n_in,
                              void* d_out, int out_size, void* d_ws, size_t ws_size,
                              hipStream_t stream) {
    const float* x    = (const float*)d_in[0];
    const float* adj  = (const float*)d_in[1];
    const int*   mask = (const int*)  d_in[2];
    const float* W1   = (const float*)d_in[3];
    const float* b1   = (const float*)d_in[4];
    const float* W2   = (const float*)d_in[5];
    const float* b2   = (const float*)d_in[6];
    const float* eps  = (const float*)d_in[7];
    float* out = (float*)d_out;
    s16x8* wfrag = (s16x8*)d_ws;   // 32 KB: 2048 units

    wpack<<<dim3(8), dim3(256), 0, stream>>>(W1, W2, wfrag);
    gin_main<<<dim3(64 * 16), dim3(256), 0, stream>>>(x, adj, mask, b1, b2, eps, wfrag, out);
}